// Round 8
// baseline (81.675 us; speedup 1.0000x reference)
//
#include <hip/hip_runtime.h>

#define NB   256        // bins per batch (power of two, == TPB)
#define TPB  256
#define NI   (NB + 1)   // intervals around/between sorted bins
#define G    256        // chunks per batch -> 1024 blocks = 4/CU (latency hiding)
#define PPT  3          // max points per thread (CH = 616 = 2*256 + 104)
#define MINF 1e30f
#define CAPD 1e15f      // cap so d*d == 1e30 == reference BIG when a side is empty

// ---- kernel 1 (tiny): bitonic-sort each batch's bins + init gbin/counter ----
__global__ __launch_bounds__(NB) void k_sort(const float* __restrict__ bc,
                                             float* __restrict__ sbins,
                                             unsigned* __restrict__ gbin,
                                             unsigned* __restrict__ counter) {
    __shared__ float s[NB];
    const int tid = threadIdx.x, b = blockIdx.x;
    s[tid] = bc[b * NB + tid];
    gbin[b * NB + tid] = 0xFFFFFFFFu;   // identity for uint atomicMin on nonneg floats
    if (b == 0 && tid == 0) counter[0] = 0u;
    __syncthreads();
    for (int k = 2; k <= NB; k <<= 1)
        for (int j = k >> 1; j > 0; j >>= 1) {
            const int ixj = tid ^ j;
            if (ixj > tid) {
                const float a = s[tid], bv = s[ixj];
                if ((a > bv) == ((tid & k) == 0)) { s[tid] = bv; s[ixj] = a; }
            }
            __syncthreads();
        }
    sbins[b * NB + tid] = s[tid];
    // dispatch boundary release/acquire makes these visible to k_main
}

// ---- kernel 2: per-point search + interval scan + last-block finalize ----
__global__ __launch_bounds__(TPB) void k_main(
    const float* __restrict__ sbins, const float* __restrict__ gt,
    int B, int V, int CH,
    unsigned* __restrict__ gbin,     // [B*NB] min d^2 bits (atomicMin)
    unsigned* __restrict__ counter,  // [1]
    unsigned* __restrict__ sumP,     // [B*G] per-block dir-1 sum bits (atomicExch)
    unsigned* __restrict__ cntP,     // [B*G] per-block valid count (atomicExch)
    float* __restrict__ out)
{
    const int b   = blockIdx.x / G;
    const int blk = blockIdx.x % G;
    const int tid = threadIdx.x;

    __shared__ float    c[NB];
    __shared__ unsigned imn[NI], imx[NI];
    __shared__ float    pm[NB], sm[NB];
    __shared__ float r4[4]; __shared__ int i4[4]; __shared__ float q4[4];
    __shared__ float ssa[8]; __shared__ int sn[8];
    __shared__ unsigned s_old;

    c[tid] = sbins[b * NB + tid];
    for (int t = tid; t < NI; t += TPB) { imn[t] = 0xFFFFFFFFu; imx[t] = 0u; }

    const int start = blk * CH;
    const int cn = min(CH, V - start);
    const float* __restrict__ gp = gt + (size_t)b * V + start;

    // load up to 3 points early (independent global loads)
    float q[PPT]; bool ok[PPT]; int idx[PPT];
    #pragma unroll
    for (int k = 0; k < PPT; ++k) {
        const int i = tid + k * TPB;
        const float v = (i < cn) ? gp[i] : 0.f;
        ok[k]  = (i < cn) && (v >= 0.001f);
        q[k]   = ok[k] ? v : 0.5f;   // harmless dummy for masked slots
        idx[k] = 0;
    }
    __syncthreads();

    // ---- meta binary search, 3 chains in lockstep (ILP), depth 5 ----
    // invariant after st=8: lower_bound(count of bins <= q) is in [idx, idx+8]
    #pragma unroll
    for (int st = 128; st >= 8; st >>= 1) {
        #pragma unroll
        for (int k = 0; k < PPT; ++k)
            idx[k] += (c[idx[k] + st - 1] <= q[k]) ? st : 0;
    }
    // resolve last 3 levels with two PARALLEL b128 window reads (idx 8-aligned)
    float sum = 0.f; int cnt = 0;
    #pragma unroll
    for (int k = 0; k < PPT; ++k) {
        const float4 w0 = *(const float4*)&c[idx[k]];
        const float4 w1 = *(const float4*)&c[idx[k] + 4];
        const int c8 = (w0.x <= q[k]) + (w0.y <= q[k]) + (w0.z <= q[k]) + (w0.w <= q[k])
                     + (w1.x <= q[k]) + (w1.y <= q[k]) + (w1.z <= q[k]) + (w1.w <= q[k]);
        const int L = idx[k] + c8;                    // lower_bound in [0,256]
        const float dlo = (L > 0)  ? (q[k] - c[L - 1]) : MINF;
        const float dhi = (L < NB) ? (c[L] - q[k])     : MINF;
        const float d = fminf(dlo, dhi);
        sum += ok[k] ? d * d : 0.f;
        cnt += ok[k] ? 1 : 0;
        if (ok[k]) {   // nonneg float bits order as uints -> exact LDS min/max
            atomicMin(&imn[L], __float_as_uint(q[k]));
            atomicMax(&imx[L], __float_as_uint(q[k]));
        }
    }
    __syncthreads();

    // ---- local fused scan: prefix-max of interval maxima / suffix-min of minima ----
    pm[tid] = (imx[tid]     == 0u)          ? -MINF : __uint_as_float(imx[tid]);
    sm[tid] = (imn[tid + 1] == 0xFFFFFFFFu) ?  MINF : __uint_as_float(imn[tid + 1]);
    __syncthreads();
    for (int off = 1; off < NB; off <<= 1) {
        const float vp = pm[tid], vs = sm[tid];
        const float op = (tid >= off)     ? pm[tid - off] : -MINF;
        const float os = (tid + off < NB) ? sm[tid + off] :  MINF;
        __syncthreads();
        pm[tid] = fmaxf(vp, op);
        sm[tid] = fminf(vs, os);
        __syncthreads();
    }
    // per-bin candidate from THIS chunk; min over blocks == global min (monotone)
    {
        const float cj = c[tid];
        const float d  = fminf(fminf(cj - pm[tid], sm[tid] - cj), CAPD);
        atomicMin(&gbin[b * NB + tid], __float_as_uint(d * d));
    }

    // ---- deterministic block reduce of dir-1 sum + count -> write-once slots ----
    for (int off = 32; off; off >>= 1) {
        sum += __shfl_down(sum, off);
        cnt += __shfl_down(cnt, off);
    }
    if ((tid & 63) == 0) { r4[tid >> 6] = sum; i4[tid >> 6] = cnt; }
    __syncthreads();
    if (tid == 0) {
        atomicExch(&sumP[blockIdx.x], __float_as_uint(r4[0] + r4[1] + r4[2] + r4[3]));
        atomicExch(&cntP[blockIdx.x], (unsigned)(i4[0] + i4[1] + i4[2] + i4[3]));
    }

    // ---- signal (syncthreads' vmcnt drain orders it after the data atomics) ----
    __syncthreads();
    if (tid == 0) s_old = atomicAdd(counter, 1u);
    __syncthreads();
    if (s_old != (unsigned)(gridDim.x - 1)) return;   // counter started at 0
    __threadfence();   // single acquire before plain-loading published state

    // ---- finalize (same arithmetic as r6/r7) ----
    for (int bb = 0; bb < B; ++bb) {
        float s = 0.f; int cc = 0;
        for (int k = tid; k < G; k += TPB) {          // G == TPB: one round
            s  += __uint_as_float(sumP[bb * G + k]);
            cc += (int)cntP[bb * G + k];
        }
        for (int off = 32; off; off >>= 1) { s += __shfl_down(s, off); cc += __shfl_down(cc, off); }
        if ((tid & 63) == 0) { r4[tid >> 6] = s; i4[tid >> 6] = cc; }
        __syncthreads();
        if (tid == 0) { ssa[bb] = r4[0]+r4[1]+r4[2]+r4[3]; sn[bb] = i4[0]+i4[1]+i4[2]+i4[3]; }
        __syncthreads();
    }
    int Lmax = 0;
    for (int bb = 0; bb < B; ++bb) Lmax = max(Lmax, sn[bb]);

    float total = 0.f;
    for (int bb = 0; bb < B; ++bb) {
        const int   npad = Lmax - sn[bb];
        const float cj = sbins[bb * NB + tid];   // from k_sort (dispatch boundary)
        const float c2 = cj * cj;
        float bm = __uint_as_float(gbin[bb * NB + tid]);   // 1e30 (BIG) if no points
        if (npad > 0) bm = fminf(bm, c2);        // pad points sit at 0 -> dist c^2
        float s = bm, mc = c2;
        for (int off = 32; off; off >>= 1) {
            s  += __shfl_down(s, off);
            mc  = fminf(mc, __shfl_down(mc, off));
        }
        if ((tid & 63) == 0) { r4[tid >> 6] = s; q4[tid >> 6] = mc; }
        __syncthreads();
        if (tid == 0)
            total += ssa[bb]
                   + (float)npad * fminf(fminf(q4[0], q4[1]), fminf(q4[2], q4[3]))
                   + (r4[0] + r4[1] + r4[2] + r4[3]);
        __syncthreads();
    }
    if (tid == 0) out[0] = total / (float)B;     // batch_reduction = mean
}

extern "C" void kernel_launch(void* const* d_in, const int* in_sizes, int n_in,
                              void* d_out, int out_size, void* d_ws, size_t ws_size,
                              hipStream_t stream) {
    const float* bc = (const float*)d_in[0];     // [B, 256, 1]
    const float* gt = (const float*)d_in[1];     // [B, 1, H, W]
    const int B  = in_sizes[0] / NB;             // 4
    const int V  = in_sizes[1] / B;              // 157696 = 256 * 616
    const int CH = (V + G - 1) / G;              // 616 (PPT*TPB = 768 covers it)

    float*    sbins   = (float*)d_ws;                      // [B*NB]
    unsigned* gbin    = (unsigned*)(sbins + (size_t)B*NB); // [B*NB]
    unsigned* sumP    = gbin + (size_t)B * NB;             // [B*G]
    unsigned* cntP    = sumP + (size_t)B * G;              // [B*G]
    unsigned* counter = cntP + (size_t)B * G;              // [1]

    k_sort<<<B, NB, 0, stream>>>(bc, sbins, gbin, counter);
    k_main<<<B * G, TPB, 0, stream>>>(sbins, gt, B, V, CH,
                                      gbin, counter, sumP, cntP, (float*)d_out);
}

// Round 9
// 78.183 us; speedup vs baseline: 1.0447x; 1.0447x over previous
//
#include <hip/hip_runtime.h>

#define NB   256        // bins per batch (power of two, == TPB)
#define TPB  256
#define NI   (NB + 1)   // 257 intervals around/between sorted bins
#define G    128        // chunks per batch -> 512 blocks = 2/CU
#define MINF 1e30f
#define CAPD 1e15f      // cap so d*d == 1e30 == reference BIG when a side is empty

// ---- kernel 1: bitonic-sort each batch's bins + init global interval arrays ----
__global__ __launch_bounds__(NB) void k_sort(const float* __restrict__ bc,
                                             float* __restrict__ sbins,
                                             unsigned* __restrict__ gmin,
                                             unsigned* __restrict__ gmax) {
    __shared__ float s[NB];
    const int tid = threadIdx.x, b = blockIdx.x;
    s[tid] = bc[b * NB + tid];
    // init atomic-reduce targets (runs before k_main; stream order guarantees visibility)
    for (int t = tid; t < NI; t += NB) {
        gmin[b * NI + t] = 0xFFFFFFFFu;   // identity for uint atomicMin on nonneg floats
        gmax[b * NI + t] = 0u;            // identity for uint atomicMax on nonneg floats
    }
    __syncthreads();
    for (int k = 2; k <= NB; k <<= 1)
        for (int j = k >> 1; j > 0; j >>= 1) {
            const int ixj = tid ^ j;
            if (ixj > tid) {
                const float a = s[tid], bv = s[ixj];
                if ((a > bv) == ((tid & k) == 0)) { s[tid] = bv; s[ixj] = a; }
            }
            __syncthreads();
        }
    sbins[b * NB + tid] = s[tid];
}

// ---- kernel 2: per point: binary-search sorted bins -> dir-1 sum + count;
//      per-interval point min/max via LDS, then ONE device atomic per interval ----
__global__ __launch_bounds__(TPB) void k_main(
    const float* __restrict__ sbins, const float* __restrict__ gt,
    int V, int CH,
    float* __restrict__ sumA_part, int* __restrict__ cnt_part,
    unsigned* __restrict__ gmin, unsigned* __restrict__ gmax)
{
    const int b   = blockIdx.x / G;
    const int blk = blockIdx.x % G;
    const int tid = threadIdx.x;
    const int start = blk * CH;
    const int cn = min(CH, V - start);
    const float* __restrict__ gp = gt + (size_t)b * V + start;

    __shared__ float    c[NB];
    __shared__ unsigned imn[NI], imx[NI];
    c[tid] = sbins[b * NB + tid];
    for (int t = tid; t < NI; t += TPB) { imn[t] = 0xFFFFFFFFu; imx[t] = 0u; }
    __syncthreads();

    float sum = 0.f; int cnt = 0;
    for (int i = tid; i < cn; i += TPB) {
        const float q = gp[i];
        if (q >= 0.001f) {
            // branchless lower-bound: idx = #bins <= q, in [0,256]
            int idx = 0;
            #pragma unroll
            for (int st = 128; st >= 1; st >>= 1)
                idx += (c[idx + st - 1] <= q) ? st : 0;
            idx += (c[idx] <= q) ? 1 : 0;   // only fires when idx==255 & c[255]<=q
            const float dlo = (idx > 0)  ? (q - c[idx - 1]) : MINF;
            const float dhi = (idx < NB) ? (c[idx] - q)     : MINF;
            const float d = fminf(dlo, dhi);
            sum += d * d; ++cnt;
            // nonneg float bits order as uints -> exact LDS min/max
            atomicMin(&imn[idx], __float_as_uint(q));
            atomicMax(&imx[idx], __float_as_uint(q));
        }
    }
    __syncthreads();

    // one device atomic per NON-EMPTY interval (2056 addrs total, <=G hits each)
    for (int t = tid; t < NI; t += TPB) {
        const unsigned lo = imn[t], hi = imx[t];
        if (lo != 0xFFFFFFFFu) atomicMin(&gmin[b * NI + t], lo);
        if (hi != 0u)          atomicMax(&gmax[b * NI + t], hi);
    }

    // deterministic block reduce of dir-1 sum + valid count
    for (int off = 32; off; off >>= 1) {
        sum += __shfl_down(sum, off);
        cnt += __shfl_down(cnt, off);
    }
    __shared__ float r4[4]; __shared__ int i4[4];
    if ((tid & 63) == 0) { r4[tid >> 6] = sum; i4[tid >> 6] = cnt; }
    __syncthreads();
    if (tid == 0) {
        sumA_part[blockIdx.x] = r4[0] + r4[1] + r4[2] + r4[3];
        cnt_part [blockIdx.x] = i4[0] + i4[1] + i4[2] + i4[3];
    }
}

// ---- kernel 3: tiny finalize (1 block): partial sums + scans + mean ----
__global__ __launch_bounds__(TPB) void k_final(
    const float* __restrict__ sbins,
    const float* __restrict__ sumA_part, const int* __restrict__ cnt_part,
    const unsigned* __restrict__ gmin, const unsigned* __restrict__ gmax,
    int B, float* __restrict__ out)
{
    const int tid = threadIdx.x;
    __shared__ float pm[NB], sm[NB];
    __shared__ float r4[4]; __shared__ int i4[4]; __shared__ float q4[4];
    __shared__ float ssa[8]; __shared__ int sn[8];

    // per-batch dir-1 sum + valid count (Lmax needs all batches first)
    for (int bb = 0; bb < B; ++bb) {
        float s = 0.f; int cc = 0;
        for (int k = tid; k < G; k += TPB) {      // G==TPB/2: one coalesced round
            s  += sumA_part[bb * G + k];
            cc += cnt_part [bb * G + k];
        }
        for (int off = 32; off; off >>= 1) { s += __shfl_down(s, off); cc += __shfl_down(cc, off); }
        if ((tid & 63) == 0) { r4[tid >> 6] = s; i4[tid >> 6] = cc; }
        __syncthreads();
        if (tid == 0) { ssa[bb] = r4[0]+r4[1]+r4[2]+r4[3]; sn[bb] = i4[0]+i4[1]+i4[2]+i4[3]; }
        __syncthreads();
    }
    int Lmax = 0;
    for (int bb = 0; bb < B; ++bb) Lmax = max(Lmax, sn[bb]);

    float total = 0.f;
    for (int bb = 0; bb < B; ++bb) {
        // interval max (for pred, entries 0..255) / min (for succ, entries 1..256)
        const unsigned hib = gmax[bb * NI + tid];
        const unsigned lob = gmin[bb * NI + tid + 1];
        pm[tid] = (hib == 0u)          ? -MINF : __uint_as_float(hib);
        sm[tid] = (lob == 0xFFFFFFFFu) ?  MINF : __uint_as_float(lob);
        __syncthreads();
        // fused Hillis-Steele: inclusive prefix-max(pm) + inclusive suffix-min(sm)
        for (int off = 1; off < NB; off <<= 1) {
            const float vp = pm[tid], vs = sm[tid];
            const float op = (tid >= off)     ? pm[tid - off] : -MINF;
            const float os = (tid + off < NB) ? sm[tid + off] :  MINF;
            __syncthreads();
            pm[tid] = fmaxf(vp, op);
            sm[tid] = fminf(vs, os);
            __syncthreads();
        }
        // bin tid: pred = max point < c, succ = min point >= c
        const float cj = sbins[bb * NB + tid];
        const float c2 = cj * cj;
        const float d  = fminf(fminf(cj - pm[tid], sm[tid] - cj), CAPD);
        float bm = d * d;                       // == 1e30 (BIG) if no valid points
        const int npad = Lmax - sn[bb];
        if (npad > 0) bm = fminf(bm, c2);       // pad points sit at 0 -> dist c^2
        float s = bm, mc = c2;
        for (int off = 32; off; off >>= 1) {
            s  += __shfl_down(s, off);
            mc  = fminf(mc, __shfl_down(mc, off));
        }
        if ((tid & 63) == 0) { r4[tid >> 6] = s; q4[tid >> 6] = mc; }
        __syncthreads();
        if (tid == 0)
            total += ssa[bb]
                   + (float)npad * fminf(fminf(q4[0], q4[1]), fminf(q4[2], q4[3]))
                   + (r4[0] + r4[1] + r4[2] + r4[3]);
        __syncthreads();
    }
    if (tid == 0) out[0] = total / (float)B;    // batch_reduction = mean
}

extern "C" void kernel_launch(void* const* d_in, const int* in_sizes, int n_in,
                              void* d_out, int out_size, void* d_ws, size_t ws_size,
                              hipStream_t stream) {
    const float* bc = (const float*)d_in[0];    // [B, 256, 1]
    const float* gt = (const float*)d_in[1];    // [B, 1, H, W]
    const int B  = in_sizes[0] / NB;            // 4
    const int V  = in_sizes[1] / B;             // 157696
    const int CH = (V + G - 1) / G;             // 1232

    float*    sbins     = (float*)d_ws;                         // [B, NB]
    float*    sumA_part = sbins + (size_t)B * NB;               // [B*G]
    int*      cnt_part  = (int*)(sumA_part + (size_t)B * G);    // [B*G]
    unsigned* gmin      = (unsigned*)(cnt_part + (size_t)B * G);// [B, NI]
    unsigned* gmax      = gmin + (size_t)B * NI;                // [B, NI]

    k_sort <<<B, NB, 0, stream>>>(bc, sbins, gmin, gmax);
    k_main <<<B * G, TPB, 0, stream>>>(sbins, gt, V, CH,
                                       sumA_part, cnt_part, gmin, gmax);
    k_final<<<1, TPB, 0, stream>>>(sbins, sumA_part, cnt_part,
                                   gmin, gmax, B, (float*)d_out);
}